// Round 8
// baseline (404.547 us; speedup 1.0000x reference)
//
#include <hip/hip_runtime.h>
#include <hip/hip_bf16.h>

constexpr int NN = 8192;
using uint = unsigned int;

typedef __bf16 bf16x8 __attribute__((ext_vector_type(8)));
typedef float f32x4 __attribute__((ext_vector_type(4)));
typedef float f32x16 __attribute__((ext_vector_type(16)));
typedef unsigned short ushort8_t __attribute__((ext_vector_type(8)));

__device__ __forceinline__ float eluf(float z) { return z > 0.f ? z : __expf(z) - 1.f; }

__device__ __forceinline__ unsigned short bf16_hi(float v) {
  unsigned u = __float_as_uint(v);
  unsigned r = u + 0x7fffu + ((u >> 16) & 1u);
  return (unsigned short)(r >> 16);
}
__device__ __forceinline__ float bf16_tof(unsigned short u) {
  return __uint_as_float(((unsigned)u) << 16);
}

// Pack 2 f32 -> 2 bf16 in one inst (lo<-a, hi<-b). RNE on gfx950.
__device__ __forceinline__ uint cvt_pk_bf16(float a, float b) {
  uint r;
  asm("v_cvt_pk_bf16_f32 %0, %1, %2" : "=v"(r) : "v"(a), "v"(b));
  return r;
}

// LDS-only barrier: order LDS ops across the barrier WITHOUT draining vmcnt.
__device__ __forceinline__ void lds_barrier() {
  asm volatile("s_waitcnt lgkmcnt(0)" ::: "memory");
  __builtin_amdgcn_s_barrier();
}

// ---------------------------------------------------------------------------
// GEMM: C[M][NOUT] = A[M][K] @ W[K][NOUT]   (fp32, BM=64,BN=64,BK=16, 4x4 micro)
// ---------------------------------------------------------------------------
template<int K, int NOUT>
__global__ __launch_bounds__(256) void gemm_kernel(
    const float* __restrict__ A, const float* __restrict__ W, float* __restrict__ C) {
  constexpr int BM = 64, BN = 64, BK = 16;
  __shared__ __align__(16) float As[BK][BM + 4];
  __shared__ __align__(16) float Ws[BK][BN];
  const int t = threadIdx.x;
  const int i0 = blockIdx.x * BM;
  const int c0 = blockIdx.y * BN;
  const int tr = t >> 4;
  const int tc = t & 15;
  const int lr = t >> 2;
  const int lk = (t & 3) * 4;
  const int wk = t >> 4;
  const int wc = (t & 15) * 4;
  float acc[4][4] = {};
  for (int k0 = 0; k0 < K; k0 += BK) {
    const float4 a4 = *reinterpret_cast<const float4*>(&A[(size_t)(i0 + lr) * K + k0 + lk]);
    As[lk + 0][lr] = a4.x; As[lk + 1][lr] = a4.y;
    As[lk + 2][lr] = a4.z; As[lk + 3][lr] = a4.w;
    *reinterpret_cast<float4*>(&Ws[wk][wc]) =
        *reinterpret_cast<const float4*>(&W[(size_t)(k0 + wk) * NOUT + c0 + wc]);
    __syncthreads();
    #pragma unroll
    for (int kk = 0; kk < BK; ++kk) {
      const float4 av = *reinterpret_cast<const float4*>(&As[kk][4 * tr]);
      const float4 wv = *reinterpret_cast<const float4*>(&Ws[kk][4 * tc]);
      const float a[4] = {av.x, av.y, av.z, av.w};
      const float w[4] = {wv.x, wv.y, wv.z, wv.w};
      #pragma unroll
      for (int i = 0; i < 4; ++i)
        #pragma unroll
        for (int j = 0; j < 4; ++j) acc[i][j] += a[i] * w[j];
    }
    __syncthreads();
  }
  #pragma unroll
  for (int i = 0; i < 4; ++i) {
    const float4 o = make_float4(acc[i][0], acc[i][1], acc[i][2], acc[i][3]);
    *reinterpret_cast<float4*>(&C[(size_t)(i0 + 4 * tr + i) * NOUT + c0 + 4 * tc]) = o;
  }
}

// ---------------------------------------------------------------------------
// s[i] = h[i].a_self ; n[i] = h[i].a_neigh   (one wave per row)
// ---------------------------------------------------------------------------
template<int FOUT>
__global__ __launch_bounds__(256) void sn_kernel(
    const float* __restrict__ H, const float* __restrict__ a_self,
    const float* __restrict__ a_neigh, float* __restrict__ s, float* __restrict__ n) {
  const int wave = threadIdx.x >> 6;
  const int lane = threadIdx.x & 63;
  const int row = blockIdx.x * 4 + wave;
  float ds = 0.f, dn = 0.f;
  #pragma unroll
  for (int c = lane; c < FOUT; c += 64) {
    const float h = H[(size_t)row * FOUT + c];
    ds += h * a_self[c];
    dn += h * a_neigh[c];
  }
  #pragma unroll
  for (int off = 32; off > 0; off >>= 1) {
    ds += __shfl_down(ds, off);
    dn += __shfl_down(dn, off);
  }
  if (lane == 0) { s[row] = ds; n[row] = dn; }
}

// ---------------------------------------------------------------------------
// Split H (fp32 [N][F]) into hi/lo bf16 in MFMA-staging layout:
//   T[tile=j/32][kc8=0..3][col=0..F-1][e=0..7]  (element j = tile*32+kc8*8+e)
// ---------------------------------------------------------------------------
template<int F>
__global__ __launch_bounds__(256) void split_kernel(
    const float* __restrict__ H, unsigned short* __restrict__ Th,
    unsigned short* __restrict__ Tl) {
  const int t = threadIdx.x;
  const int tile = blockIdx.x;
  const int c = t & (F - 1);
  const int kcb = t / F;
  for (int kc = kcb; kc < 4; kc += 256 / F) {
    ushort8_t hi, lo;
    #pragma unroll
    for (int e = 0; e < 8; ++e) {
      float v = H[(size_t)(tile * 32 + kc * 8 + e) * F + c];
      unsigned short h = bf16_hi(v);
      hi[e] = h;
      lo[e] = bf16_hi(v - bf16_tof(h));
    }
    size_t o = ((size_t)(tile * 4 + kc) * F + c) * 8;
    *reinterpret_cast<ushort8_t*>(&Th[o]) = hi;
    *reinterpret_cast<ushort8_t*>(&Tl[o]) = lo;
  }
}

// ---------------------------------------------------------------------------
// adj (int32 0/1) -> bitmask, word W covers cols [W*32, W*32+32) of a row.
// ---------------------------------------------------------------------------
__global__ __launch_bounds__(256) void mask_kernel(
    const int* __restrict__ adj, uint* __restrict__ Bm) {
  const size_t tg = (size_t)blockIdx.x * 256 + threadIdx.x;
  const int4 a = *reinterpret_cast<const int4*>(&adj[tg * 4]);
  uint nib = (a.x > 0 ? 1u : 0u) | (a.y > 0 ? 2u : 0u) |
             (a.z > 0 ? 4u : 0u) | (a.w > 0 ? 8u : 0u);
  const int lane = threadIdx.x & 63;
  uint v = nib << ((lane & 7) * 4);
  v |= __shfl_xor(v, 1);
  v |= __shfl_xor(v, 2);
  v |= __shfl_xor(v, 4);
  if ((lane & 7) == 0) Bm[tg >> 3] = v;
}

// ---------------------------------------------------------------------------
// Layer-1 fused attention. F=256, BR=32, 1024 thr (16 waves), BC=64 k-tiles.
// Wave w: cf = w&7 (32-col frag), ks = w>>3 (k-half). P layout padded to
// 132-word group stride (bank-conflict-free writes). Two independent MFMA
// accumulator chains (kc-block 0/1). cvt_pk_bf16 packing.
// ---------------------------------------------------------------------------
__global__ __launch_bounds__(1024, 4) void attn1_kernel(
    const float* __restrict__ Mm, const uint* __restrict__ Bm,
    const float* __restrict__ sv, const float* __restrict__ nv,
    const unsigned short* __restrict__ Th, const unsigned short* __restrict__ Tl,
    float* __restrict__ out) {
  constexpr int F = 256, BR = 32, NT = NN / 64;
  __shared__ __align__(16) uint Pa[2][2][8 * 132];  // [buf][hi/lo][g*132 + row*4 + q]
  __shared__ __align__(16) float nvs[NN];           // also reused as k-reduce scratch
  __shared__ float l_lds[BR];

  const int t = threadIdx.x;
  const int lane = t & 63;
  const int w = t >> 6;              // 0..15
  const int cf = w & 7;              // col-frag (32 cols)
  const int ks = w >> 3;             // k-half
  const int r = t >> 5;              // score row 0..31
  const int p2 = t & 31;             // col pair: cols 2p2, 2p2+1 (of 64)
  const int i0 = blockIdx.x * BR;

  for (int i = t; i < NN / 4; i += 1024)
    reinterpret_cast<float4*>(nvs)[i] = reinterpret_cast<const float4*>(nv)[i];

  const float svr = sv[i0 + r];
  const size_t mrow = (size_t)(i0 + r) * NN;
  const uint* mkrow = Bm + (size_t)(i0 + r) * (NN / 32);
  const int col = cf * 32 + (lane & 31);
  const size_t bo0 = ((size_t)(lane >> 5) * F + col) * 8;  // kc8 {0,1}; +4096 for {2,3}
  const int pidx = (p2 >> 2) * 132 + r * 4 + (p2 & 3);
  const int aidx = (ks * 4 + (lane >> 5)) * 132 + (lane & 31) * 4;

  float2 M_e = *reinterpret_cast<const float2*>(&Mm[mrow + 2 * p2]);
  float2 M_o = *reinterpret_cast<const float2*>(&Mm[mrow + 64 + 2 * p2]);
  uint mk_e = mkrow[0 + (p2 >> 4)];
  uint mk_o = mkrow[2 + (p2 >> 4)];
  const size_t tb0 = (size_t)ks * 8192;   // 32-row B-tile index = 2*0+ks
  bf16x8 bh0_e = *reinterpret_cast<const bf16x8*>(Th + tb0 + bo0);
  bf16x8 bl0_e = *reinterpret_cast<const bf16x8*>(Tl + tb0 + bo0);
  bf16x8 bh1_e = *reinterpret_cast<const bf16x8*>(Th + tb0 + bo0 + 4096);
  bf16x8 bl1_e = *reinterpret_cast<const bf16x8*>(Tl + tb0 + bo0 + 4096);
  bf16x8 bh0_o, bl0_o, bh1_o, bl1_o;

  float rsum = 0.f;
  f32x16 accA, accB;
  #pragma unroll
  for (int i = 0; i < 16; ++i) { accA[i] = 0.f; accB[i] = 0.f; }

  __syncthreads();   // nvs staged

  float2 nv_e = *reinterpret_cast<const float2*>(&nvs[2 * p2]);
  float2 nv_o = *reinterpret_cast<const float2*>(&nvs[64 + 2 * p2]);

#define STEP1(TJ, MC, MKC, NVC, BH0C, BL0C, BH1C, BL1C, BH0N, BL0N, BH1N, BL1N)   \
  {                                                                               \
    const int t_j = (TJ);                                                         \
    /* 1. next-tile B loads into dead parity regs */                              \
    const int jb = (t_j + 1 < NT) ? t_j + 1 : 0;                                  \
    const size_t tb = (size_t)(2 * jb + ks) * 8192;                               \
    BH0N = *reinterpret_cast<const bf16x8*>(Th + tb + bo0);                       \
    BL0N = *reinterpret_cast<const bf16x8*>(Tl + tb + bo0);                       \
    BH1N = *reinterpret_cast<const bf16x8*>(Th + tb + bo0 + 4096);                \
    BL1N = *reinterpret_cast<const bf16x8*>(Tl + tb + bo0 + 4096);                \
    /* 2. score: consumes MC/MKC/NVC */                                           \
    float e0 = (svr + NVC.x) * MC.x; e0 = fmaxf(e0, 0.2f * e0); e0 = fminf(e0, 70.f); \
    float e1 = (svr + NVC.y) * MC.y; e1 = fmaxf(e1, 0.2f * e1); e1 = fminf(e1, 70.f); \
    const float p0 = ((MKC >> (2 * (p2 & 15))) & 1u) ? __expf(e0) : 0.f;          \
    const float p1 = ((MKC >> (2 * (p2 & 15) + 1)) & 1u) ? __expf(e1) : 0.f;      \
    rsum += p0 + p1;                                                              \
    /* 3. refill tile+2 DIRECTLY into the dead regs (no copy) */                  \
    const int jm = (t_j + 2 < NT) ? t_j + 2 : 0;                                  \
    MC = *reinterpret_cast<const float2*>(&Mm[mrow + (size_t)jm * 64 + 2 * p2]);  \
    MKC = mkrow[jm * 2 + (p2 >> 4)];                                              \
    NVC = *reinterpret_cast<const float2*>(&nvs[jm * 64 + 2 * p2]);               \
    /* 4. pack + P writes (hi/lo decomposition exact for any cvt rounding) */     \
    const uint hw = cvt_pk_bf16(p0, p1);                                          \
    const float f0 = __uint_as_float(hw << 16);                                   \
    const float f1 = __uint_as_float(hw & 0xffff0000u);                           \
    const uint lw = cvt_pk_bf16(p0 - f0, p1 - f1);                                \
    Pa[t_j & 1][0][pidx] = hw;                                                    \
    Pa[t_j & 1][1][pidx] = lw;                                                    \
    lds_barrier();                                                                \
    /* 5. MFMA over this wave's 32-k half, 2 independent chains */                \
    const uint* pb0 = &Pa[t_j & 1][0][0];                                         \
    const uint* pb1 = &Pa[t_j & 1][1][0];                                         \
    const bf16x8 ah0 = *reinterpret_cast<const bf16x8*>(&pb0[aidx]);              \
    const bf16x8 al0 = *reinterpret_cast<const bf16x8*>(&pb1[aidx]);              \
    const bf16x8 ah1 = *reinterpret_cast<const bf16x8*>(&pb0[aidx + 264]);        \
    const bf16x8 al1 = *reinterpret_cast<const bf16x8*>(&pb1[aidx + 264]);        \
    accA = __builtin_amdgcn_mfma_f32_32x32x16_bf16(al0, BH0C, accA, 0, 0, 0);     \
    accB = __builtin_amdgcn_mfma_f32_32x32x16_bf16(al1, BH1C, accB, 0, 0, 0);     \
    accA = __builtin_amdgcn_mfma_f32_32x32x16_bf16(ah0, BL0C, accA, 0, 0, 0);     \
    accB = __builtin_amdgcn_mfma_f32_32x32x16_bf16(ah1, BL1C, accB, 0, 0, 0);     \
    accA = __builtin_amdgcn_mfma_f32_32x32x16_bf16(ah0, BH0C, accA, 0, 0, 0);     \
    accB = __builtin_amdgcn_mfma_f32_32x32x16_bf16(ah1, BH1C, accB, 0, 0, 0);     \
  }

  for (int tj = 0; tj < NT; tj += 2) {
    STEP1(tj,     M_e, mk_e, nv_e, bh0_e, bl0_e, bh1_e, bl1_e, bh0_o, bl0_o, bh1_o, bl1_o)
    STEP1(tj + 1, M_o, mk_o, nv_o, bh0_o, bl0_o, bh1_o, bl1_o, bh0_e, bl0_e, bh1_e, bl1_e)
  }
#undef STEP1

  // rowsum over the 32 threads of each row
  #pragma unroll
  for (int off = 1; off < 32; off <<= 1) rsum += __shfl_xor(rsum, off);
  if (p2 == 0) l_lds[r] = rsum;
  __syncthreads();   // all score reads of nvs done; l_lds visible

  // k-half reduction through LDS (reuse nvs as scratch: 8 cf * 1024 floats)
  float* scratch = nvs;
  if (ks == 1) {
    #pragma unroll
    for (int reg = 0; reg < 16; ++reg)
      scratch[cf * 1024 + reg * 64 + lane] = accA[reg] + accB[reg];
  }
  __syncthreads();
  if (ks == 0) {
    #pragma unroll
    for (int reg = 0; reg < 16; ++reg) {
      const int row = (reg & 3) + 8 * (reg >> 2) + 4 * (lane >> 5);
      const float v = (accA[reg] + accB[reg] + scratch[cf * 1024 + reg * 64 + lane]) / l_lds[row];
      out[(size_t)(i0 + row) * F + col] = eluf(v);
    }
  }
}

// ---------------------------------------------------------------------------
// Layer-2 fused attention. F=64, BR=32, 1024 thr (16 waves), BC=64 k-tiles.
// Wave w: rb = w&1 (16-row frag), cf = (w>>1)&3 (16-col frag), ks = w>>3.
// Padded P layout; 2-chain accumulator; cvt_pk packing.
// ---------------------------------------------------------------------------
__global__ __launch_bounds__(1024, 4) void attn2_kernel(
    const float* __restrict__ Mm, const uint* __restrict__ Bm,
    const float* __restrict__ sv, const float* __restrict__ nv,
    const unsigned short* __restrict__ Th, const unsigned short* __restrict__ Tl,
    float* __restrict__ out) {
  constexpr int F = 64, BR = 32, NT = NN / 64;
  __shared__ __align__(16) uint Pa[2][2][8 * 132];
  __shared__ __align__(16) float nvs[NN];
  __shared__ float l_lds[BR];

  const int t = threadIdx.x;
  const int lane = t & 63;
  const int w = t >> 6;
  const int rb = w & 1;
  const int cf = (w >> 1) & 3;
  const int ks = w >> 3;
  const int r = t >> 5;
  const int p2 = t & 31;
  const int i0 = blockIdx.x * BR;

  for (int i = t; i < NN / 4; i += 1024)
    reinterpret_cast<float4*>(nvs)[i] = reinterpret_cast<const float4*>(nv)[i];

  const float svr = sv[i0 + r];
  const size_t mrow = (size_t)(i0 + r) * NN;
  const uint* mkrow = Bm + (size_t)(i0 + r) * (NN / 32);
  const int col = cf * 16 + (lane & 15);
  const size_t bo2 = ((size_t)(lane >> 4) * F + col) * 8;
  const int pidx = (p2 >> 2) * 132 + r * 4 + (p2 & 3);
  const int aidx = (ks * 4 + (lane >> 4)) * 132 + (rb * 16 + (lane & 15)) * 4;

  float2 M_e = *reinterpret_cast<const float2*>(&Mm[mrow + 2 * p2]);
  float2 M_o = *reinterpret_cast<const float2*>(&Mm[mrow + 64 + 2 * p2]);
  uint mk_e = mkrow[0 + (p2 >> 4)];
  uint mk_o = mkrow[2 + (p2 >> 4)];
  const size_t tb0 = (size_t)ks * 2048;
  bf16x8 bh_e = *reinterpret_cast<const bf16x8*>(Th + tb0 + bo2);
  bf16x8 bl_e = *reinterpret_cast<const bf16x8*>(Tl + tb0 + bo2);
  bf16x8 bh_o, bl_o;

  float rsum = 0.f;
  f32x4 accA = {0.f, 0.f, 0.f, 0.f};
  f32x4 accB = {0.f, 0.f, 0.f, 0.f};

  __syncthreads();   // nvs staged

  float2 nv_e = *reinterpret_cast<const float2*>(&nvs[2 * p2]);
  float2 nv_o = *reinterpret_cast<const float2*>(&nvs[64 + 2 * p2]);

#define STEP2(TJ, MC, MKC, NVC, BHC, BLC, BHN, BLN)                               \
  {                                                                               \
    const int t_j = (TJ);                                                         \
    const int jb = (t_j + 1 < NT) ? t_j + 1 : 0;                                  \
    const size_t tb = (size_t)(2 * jb + ks) * 2048;                               \
    BHN = *reinterpret_cast<const bf16x8*>(Th + tb + bo2);                        \
    BLN = *reinterpret_cast<const bf16x8*>(Tl + tb + bo2);                        \
    float e0 = (svr + NVC.x) * MC.x; e0 = fmaxf(e0, 0.2f * e0); e0 = fminf(e0, 70.f); \
    float e1 = (svr + NVC.y) * MC.y; e1 = fmaxf(e1, 0.2f * e1); e1 = fminf(e1, 70.f); \
    const float p0 = ((MKC >> (2 * (p2 & 15))) & 1u) ? __expf(e0) : 0.f;          \
    const float p1 = ((MKC >> (2 * (p2 & 15) + 1)) & 1u) ? __expf(e1) : 0.f;      \
    rsum += p0 + p1;                                                              \
    const int jm = (t_j + 2 < NT) ? t_j + 2 : 0;                                  \
    MC = *reinterpret_cast<const float2*>(&Mm[mrow + (size_t)jm * 64 + 2 * p2]);  \
    MKC = mkrow[jm * 2 + (p2 >> 4)];                                              \
    NVC = *reinterpret_cast<const float2*>(&nvs[jm * 64 + 2 * p2]);               \
    const uint hw = cvt_pk_bf16(p0, p1);                                          \
    const float f0 = __uint_as_float(hw << 16);                                   \
    const float f1 = __uint_as_float(hw & 0xffff0000u);                           \
    const uint lw = cvt_pk_bf16(p0 - f0, p1 - f1);                                \
    Pa[t_j & 1][0][pidx] = hw;                                                    \
    Pa[t_j & 1][1][pidx] = lw;                                                    \
    lds_barrier();                                                                \
    const bf16x8 ah = *reinterpret_cast<const bf16x8*>(&Pa[t_j & 1][0][aidx]);    \
    const bf16x8 al = *reinterpret_cast<const bf16x8*>(&Pa[t_j & 1][1][aidx]);    \
    accA = __builtin_amdgcn_mfma_f32_16x16x32_bf16(al, BHC, accA, 0, 0, 0);       \
    accB = __builtin_amdgcn_mfma_f32_16x16x32_bf16(ah, BLC, accB, 0, 0, 0);       \
    accA = __builtin_amdgcn_mfma_f32_16x16x32_bf16(ah, BHC, accA, 0, 0, 0);       \
  }

  for (int tj = 0; tj < NT; tj += 2) {
    STEP2(tj,     M_e, mk_e, nv_e, bh_e, bl_e, bh_o, bl_o)
    STEP2(tj + 1, M_o, mk_o, nv_o, bh_o, bl_o, bh_e, bl_e)
  }
#undef STEP2

  #pragma unroll
  for (int off = 1; off < 32; off <<= 1) rsum += __shfl_xor(rsum, off);
  if (p2 == 0) l_lds[r] = rsum;
  __syncthreads();

  // k-half reduction through LDS scratch (reuse nvs: 8 * 256 floats)
  float* scratch = nvs;
  if (ks == 1) {
    #pragma unroll
    for (int reg = 0; reg < 4; ++reg)
      scratch[(w & 7) * 256 + reg * 64 + lane] = accA[reg] + accB[reg];
  }
  __syncthreads();
  if (ks == 0) {
    #pragma unroll
    for (int reg = 0; reg < 4; ++reg) {
      const int row = rb * 16 + (lane >> 4) * 4 + reg;
      const float v = (accA[reg] + accB[reg] + scratch[w * 256 + reg * 64 + lane]) / l_lds[row];
      out[(size_t)(i0 + row) * F + col] = eluf(v);
    }
  }
}

// ---------------------------------------------------------------------------
extern "C" void kernel_launch(void* const* d_in, const int* in_sizes, int n_in,
                              void* d_out, int out_size, void* d_ws, size_t ws_size,
                              hipStream_t stream) {
  const float* x   = (const float*)d_in[0];
  const int*   adj = (const int*)  d_in[1];
  const float* Mm  = (const float*)d_in[2];
  const float* W0  = (const float*)d_in[3];
  const float* as0 = (const float*)d_in[4];
  const float* an0 = (const float*)d_in[5];
  const float* W1  = (const float*)d_in[6];
  const float* as1 = (const float*)d_in[7];
  const float* an1 = (const float*)d_in[8];
  float* out = (float*)d_out;

  char* ws = (char*)d_ws;
  const size_t MB = 1048576;
  float* h0  = (float*)(ws);                              // 8 MB (dead after split1)
  uint*  Bm  = (uint*) (ws);                              // 8 MB (written after split1)
  float* x1  = (float*)(ws + 8 * MB);                     // 8 MB
  float* h1  = (float*)(ws + 16 * MB);                    // 2 MB
  unsigned short* Th0 = (unsigned short*)(ws + 18 * MB);  // 4 MB
  unsigned short* Tl0 = (unsigned short*)(ws + 22 * MB);  // 4 MB
  unsigned short* Th1 = (unsigned short*)(ws + 26 * MB);  // 1 MB
  unsigned short* Tl1 = (unsigned short*)(ws + 27 * MB);  // 1 MB
  float* s0 = (float*)(ws + 28 * MB);
  float* n0 = s0 + NN;
  float* s1 = n0 + NN;
  float* n1 = s1 + NN;

  // ---- layer 1 ----
  gemm_kernel<512, 256><<<dim3(128, 4), dim3(256), 0, stream>>>(x, W0, h0);
  sn_kernel<256><<<dim3(2048), dim3(256), 0, stream>>>(h0, as0, an0, s0, n0);
  split_kernel<256><<<dim3(256), dim3(256), 0, stream>>>(h0, Th0, Tl0);
  mask_kernel<<<dim3(65536), dim3(256), 0, stream>>>(adj, Bm);   // h0 now dead
  attn1_kernel<<<dim3(256), dim3(1024), 0, stream>>>(Mm, Bm, s0, n0, Th0, Tl0, x1);
  // ---- layer 2 ----
  gemm_kernel<256, 64><<<dim3(128, 1), dim3(256), 0, stream>>>(x1, W1, h1);
  sn_kernel<64><<<dim3(2048), dim3(256), 0, stream>>>(h1, as1, an1, s1, n1);
  split_kernel<64><<<dim3(256), dim3(256), 0, stream>>>(h1, Th1, Tl1);
  attn2_kernel<<<dim3(256), dim3(1024), 0, stream>>>(Mm, Bm, s1, n1, Th1, Tl1, out);
}

// Round 9
// 335.171 us; speedup vs baseline: 1.2070x; 1.2070x over previous
//
#include <hip/hip_runtime.h>
#include <hip/hip_bf16.h>

constexpr int NN = 8192;
using uint = unsigned int;

typedef __bf16 bf16x8 __attribute__((ext_vector_type(8)));
typedef float f32x4 __attribute__((ext_vector_type(4)));
typedef float f32x16 __attribute__((ext_vector_type(16)));
typedef unsigned short ushort8_t __attribute__((ext_vector_type(8)));

__device__ __forceinline__ float eluf(float z) { return z > 0.f ? z : __expf(z) - 1.f; }

__device__ __forceinline__ unsigned short bf16_hi(float v) {
  unsigned u = __float_as_uint(v);
  unsigned r = u + 0x7fffu + ((u >> 16) & 1u);
  return (unsigned short)(r >> 16);
}
__device__ __forceinline__ float bf16_tof(unsigned short u) {
  return __uint_as_float(((unsigned)u) << 16);
}

// Pack 2 f32 -> 2 bf16 in one inst (lo<-a, hi<-b).
__device__ __forceinline__ uint cvt_pk_bf16(float a, float b) {
  uint r;
  asm("v_cvt_pk_bf16_f32 %0, %1, %2" : "=v"(r) : "v"(a), "v"(b));
  return r;
}

// LDS-only barrier: order LDS ops across the barrier WITHOUT draining vmcnt.
__device__ __forceinline__ void lds_barrier() {
  asm volatile("s_waitcnt lgkmcnt(0)" ::: "memory");
  __builtin_amdgcn_s_barrier();
}

// ---------------------------------------------------------------------------
// GEMM: C[M][NOUT] = A[M][K] @ W[K][NOUT]   (fp32, BM=64,BN=64,BK=16, 4x4 micro)
// ---------------------------------------------------------------------------
template<int K, int NOUT>
__global__ __launch_bounds__(256) void gemm_kernel(
    const float* __restrict__ A, const float* __restrict__ W, float* __restrict__ C) {
  constexpr int BM = 64, BN = 64, BK = 16;
  __shared__ __align__(16) float As[BK][BM + 4];
  __shared__ __align__(16) float Ws[BK][BN];
  const int t = threadIdx.x;
  const int i0 = blockIdx.x * BM;
  const int c0 = blockIdx.y * BN;
  const int tr = t >> 4;
  const int tc = t & 15;
  const int lr = t >> 2;
  const int lk = (t & 3) * 4;
  const int wk = t >> 4;
  const int wc = (t & 15) * 4;
  float acc[4][4] = {};
  for (int k0 = 0; k0 < K; k0 += BK) {
    const float4 a4 = *reinterpret_cast<const float4*>(&A[(size_t)(i0 + lr) * K + k0 + lk]);
    As[lk + 0][lr] = a4.x; As[lk + 1][lr] = a4.y;
    As[lk + 2][lr] = a4.z; As[lk + 3][lr] = a4.w;
    *reinterpret_cast<float4*>(&Ws[wk][wc]) =
        *reinterpret_cast<const float4*>(&W[(size_t)(k0 + wk) * NOUT + c0 + wc]);
    __syncthreads();
    #pragma unroll
    for (int kk = 0; kk < BK; ++kk) {
      const float4 av = *reinterpret_cast<const float4*>(&As[kk][4 * tr]);
      const float4 wv = *reinterpret_cast<const float4*>(&Ws[kk][4 * tc]);
      const float a[4] = {av.x, av.y, av.z, av.w};
      const float w[4] = {wv.x, wv.y, wv.z, wv.w};
      #pragma unroll
      for (int i = 0; i < 4; ++i)
        #pragma unroll
        for (int j = 0; j < 4; ++j) acc[i][j] += a[i] * w[j];
    }
    __syncthreads();
  }
  #pragma unroll
  for (int i = 0; i < 4; ++i) {
    const float4 o = make_float4(acc[i][0], acc[i][1], acc[i][2], acc[i][3]);
    *reinterpret_cast<float4*>(&C[(size_t)(i0 + 4 * tr + i) * NOUT + c0 + 4 * tc]) = o;
  }
}

// ---------------------------------------------------------------------------
// s[i] = h[i].a_self ; n[i] = h[i].a_neigh   (one wave per row)
// ---------------------------------------------------------------------------
template<int FOUT>
__global__ __launch_bounds__(256) void sn_kernel(
    const float* __restrict__ H, const float* __restrict__ a_self,
    const float* __restrict__ a_neigh, float* __restrict__ s, float* __restrict__ n) {
  const int wave = threadIdx.x >> 6;
  const int lane = threadIdx.x & 63;
  const int row = blockIdx.x * 4 + wave;
  float ds = 0.f, dn = 0.f;
  #pragma unroll
  for (int c = lane; c < FOUT; c += 64) {
    const float h = H[(size_t)row * FOUT + c];
    ds += h * a_self[c];
    dn += h * a_neigh[c];
  }
  #pragma unroll
  for (int off = 32; off > 0; off >>= 1) {
    ds += __shfl_down(ds, off);
    dn += __shfl_down(dn, off);
  }
  if (lane == 0) { s[row] = ds; n[row] = dn; }
}

// ---------------------------------------------------------------------------
// Split H (fp32 [N][F]) into hi/lo bf16 in MFMA-staging layout:
//   T[tile=j/32][kc8=0..3][col=0..F-1][e=0..7]  (element j = tile*32+kc8*8+e)
// ---------------------------------------------------------------------------
template<int F>
__global__ __launch_bounds__(256) void split_kernel(
    const float* __restrict__ H, unsigned short* __restrict__ Th,
    unsigned short* __restrict__ Tl) {
  const int t = threadIdx.x;
  const int tile = blockIdx.x;
  const int c = t & (F - 1);
  const int kcb = t / F;
  for (int kc = kcb; kc < 4; kc += 256 / F) {
    ushort8_t hi, lo;
    #pragma unroll
    for (int e = 0; e < 8; ++e) {
      float v = H[(size_t)(tile * 32 + kc * 8 + e) * F + c];
      unsigned short h = bf16_hi(v);
      hi[e] = h;
      lo[e] = bf16_hi(v - bf16_tof(h));
    }
    size_t o = ((size_t)(tile * 4 + kc) * F + c) * 8;
    *reinterpret_cast<ushort8_t*>(&Th[o]) = hi;
    *reinterpret_cast<ushort8_t*>(&Tl[o]) = lo;
  }
}

// ---------------------------------------------------------------------------
// adj (int32 0/1) -> bitmask, word W covers cols [W*32, W*32+32) of a row.
// ---------------------------------------------------------------------------
__global__ __launch_bounds__(256) void mask_kernel(
    const int* __restrict__ adj, uint* __restrict__ Bm) {
  const size_t tg = (size_t)blockIdx.x * 256 + threadIdx.x;
  const int4 a = *reinterpret_cast<const int4*>(&adj[tg * 4]);
  uint nib = (a.x > 0 ? 1u : 0u) | (a.y > 0 ? 2u : 0u) |
             (a.z > 0 ? 4u : 0u) | (a.w > 0 ? 8u : 0u);
  const int lane = threadIdx.x & 63;
  uint v = nib << ((lane & 7) * 4);
  v |= __shfl_xor(v, 1);
  v |= __shfl_xor(v, 2);
  v |= __shfl_xor(v, 4);
  if ((lane & 7) == 0) Bm[tg >> 3] = v;
}

// ---------------------------------------------------------------------------
// combine: out = elu((pO[0]+pO[1]) / (pL[0]+pL[1]))   (j-half partial merge)
// ---------------------------------------------------------------------------
template<int F>
__global__ __launch_bounds__(256) void combine_kernel(
    const float* __restrict__ pO, const float* __restrict__ pL, float* __restrict__ out) {
  const size_t q = (size_t)blockIdx.x * 256 + threadIdx.x;
  const size_t base = q * 4;
  const int row = (int)(base / F);
  const float4 a = *reinterpret_cast<const float4*>(pO + base);
  const float4 b = *reinterpret_cast<const float4*>(pO + (size_t)8192 * F + base);
  const float il = 1.0f / (pL[row] + pL[8192 + row]);
  float4 o;
  o.x = eluf((a.x + b.x) * il);
  o.y = eluf((a.y + b.y) * il);
  o.z = eluf((a.z + b.z) * il);
  o.w = eluf((a.w + b.w) * il);
  *reinterpret_cast<float4*>(out + base) = o;
}

// ---------------------------------------------------------------------------
// Layer-1 fused attention. Grid (128,2): block = 64 rows (2 rowgroups) x j-half.
// 1024 thr (16 waves): cf = w&7 (32-col frag), ks = w>>3 (k-half of 64-tile).
// Per STEP: scores for both rowgroups (4/thread), B-frags loaded ONCE and
// reused by both rowgroups' MFMAs (12 MFMAs, 2 chains). Partial out + rowsum.
// ---------------------------------------------------------------------------
__global__ __launch_bounds__(1024, 4) void attn1_kernel(
    const float* __restrict__ Mm, const uint* __restrict__ Bm,
    const float* __restrict__ sv, const float* __restrict__ nv,
    const unsigned short* __restrict__ Th, const unsigned short* __restrict__ Tl,
    float* __restrict__ pO, float* __restrict__ pL) {
  constexpr int F = 256, NT = 4096 / 64;
  __shared__ __align__(16) uint Pa[2][2][2][8 * 132];  // [buf][part][rg][g*132+r*4+q]
  __shared__ __align__(16) float nvs[8192];            // [0..4095]=nv half; full=scratch
  __shared__ float l_lds[64];

  const int t = threadIdx.x;
  const int lane = t & 63;
  const int w = t >> 6;
  const int cf = w & 7;
  const int ks = w >> 3;
  const int r = t >> 5;              // score row 0..31 (per rowgroup)
  const int p2 = t & 31;             // col pair 2p2,2p2+1 (of 64)
  const int i0 = blockIdx.x * 64;
  const int jh = blockIdx.y;
  const size_t jbase = (size_t)jh * 4096;
  const int jt = jh * 128;           // tile32 base

  reinterpret_cast<float4*>(nvs)[t] = reinterpret_cast<const float4*>(nv + jbase)[t];

  const float svrA = sv[i0 + r];
  const float svrB = sv[i0 + 32 + r];
  const size_t mrowA = (size_t)(i0 + r) * NN + jbase;
  const size_t mrowB = mrowA + (size_t)32 * NN;
  const uint* mkrowA = Bm + (size_t)(i0 + r) * (NN / 32) + jh * 128;
  const uint* mkrowB = mkrowA + (size_t)32 * (NN / 32);
  const int col = cf * 32 + (lane & 31);
  const size_t bo0 = ((size_t)(lane >> 5) * F + col) * 8;
  const int pidx = (p2 >> 2) * 132 + r * 4 + (p2 & 3);
  const int aidx = (ks * 4 + (lane >> 5)) * 132 + (lane & 31) * 4;

  float2 MA_e = *reinterpret_cast<const float2*>(&Mm[mrowA + 2 * p2]);
  float2 MA_o = *reinterpret_cast<const float2*>(&Mm[mrowA + 64 + 2 * p2]);
  float2 MB_e = *reinterpret_cast<const float2*>(&Mm[mrowB + 2 * p2]);
  float2 MB_o = *reinterpret_cast<const float2*>(&Mm[mrowB + 64 + 2 * p2]);
  uint mkA_e = mkrowA[p2 >> 4];
  uint mkA_o = mkrowA[2 + (p2 >> 4)];
  uint mkB_e = mkrowB[p2 >> 4];
  uint mkB_o = mkrowB[2 + (p2 >> 4)];
  const size_t tb0 = (size_t)(jt + ks) * 8192;
  bf16x8 bh0_e = *reinterpret_cast<const bf16x8*>(Th + tb0 + bo0);
  bf16x8 bl0_e = *reinterpret_cast<const bf16x8*>(Tl + tb0 + bo0);
  bf16x8 bh1_e = *reinterpret_cast<const bf16x8*>(Th + tb0 + bo0 + 4096);
  bf16x8 bl1_e = *reinterpret_cast<const bf16x8*>(Tl + tb0 + bo0 + 4096);
  bf16x8 bh0_o, bl0_o, bh1_o, bl1_o;

  float rsumA = 0.f, rsumB = 0.f;
  f32x16 accA, accB;
  #pragma unroll
  for (int i = 0; i < 16; ++i) { accA[i] = 0.f; accB[i] = 0.f; }

  __syncthreads();   // nvs staged

  float2 nv_e = *reinterpret_cast<const float2*>(&nvs[2 * p2]);
  float2 nv_o = *reinterpret_cast<const float2*>(&nvs[64 + 2 * p2]);

#define STEP1(TJ, MCA, MKA, MCB, MKB, NVC, BH0C, BL0C, BH1C, BL1C, BH0N, BL0N, BH1N, BL1N) \
  {                                                                               \
    const int t_j = (TJ);                                                         \
    const int jb = (t_j + 1 < NT) ? t_j + 1 : 0;                                  \
    const size_t tb = (size_t)(jt + 2 * jb + ks) * 8192;                          \
    BH0N = *reinterpret_cast<const bf16x8*>(Th + tb + bo0);                       \
    BL0N = *reinterpret_cast<const bf16x8*>(Tl + tb + bo0);                       \
    BH1N = *reinterpret_cast<const bf16x8*>(Th + tb + bo0 + 4096);                \
    BL1N = *reinterpret_cast<const bf16x8*>(Tl + tb + bo0 + 4096);                \
    float e0 = (svrA + NVC.x) * MCA.x; e0 = fmaxf(e0, 0.2f * e0); e0 = fminf(e0, 70.f); \
    float e1 = (svrA + NVC.y) * MCA.y; e1 = fmaxf(e1, 0.2f * e1); e1 = fminf(e1, 70.f); \
    float e2 = (svrB + NVC.x) * MCB.x; e2 = fmaxf(e2, 0.2f * e2); e2 = fminf(e2, 70.f); \
    float e3 = (svrB + NVC.y) * MCB.y; e3 = fmaxf(e3, 0.2f * e3); e3 = fminf(e3, 70.f); \
    const float pA0 = ((MKA >> (2 * (p2 & 15))) & 1u) ? __expf(e0) : 0.f;         \
    const float pA1 = ((MKA >> (2 * (p2 & 15) + 1)) & 1u) ? __expf(e1) : 0.f;     \
    const float pB0 = ((MKB >> (2 * (p2 & 15))) & 1u) ? __expf(e2) : 0.f;         \
    const float pB1 = ((MKB >> (2 * (p2 & 15) + 1)) & 1u) ? __expf(e3) : 0.f;     \
    rsumA += pA0 + pA1; rsumB += pB0 + pB1;                                       \
    const int jm = (t_j + 2 < NT) ? t_j + 2 : 0;                                  \
    MCA = *reinterpret_cast<const float2*>(&Mm[mrowA + (size_t)jm * 64 + 2 * p2]); \
    MKA = mkrowA[jm * 2 + (p2 >> 4)];                                             \
    MCB = *reinterpret_cast<const float2*>(&Mm[mrowB + (size_t)jm * 64 + 2 * p2]); \
    MKB = mkrowB[jm * 2 + (p2 >> 4)];                                             \
    NVC = *reinterpret_cast<const float2*>(&nvs[jm * 64 + 2 * p2]);               \
    const uint hwA = cvt_pk_bf16(pA0, pA1);                                       \
    const uint lwA = cvt_pk_bf16(pA0 - __uint_as_float(hwA << 16),                \
                                 pA1 - __uint_as_float(hwA & 0xffff0000u));       \
    const uint hwB = cvt_pk_bf16(pB0, pB1);                                       \
    const uint lwB = cvt_pk_bf16(pB0 - __uint_as_float(hwB << 16),                \
                                 pB1 - __uint_as_float(hwB & 0xffff0000u));       \
    Pa[t_j & 1][0][0][pidx] = hwA;                                                \
    Pa[t_j & 1][1][0][pidx] = lwA;                                                \
    Pa[t_j & 1][0][1][pidx] = hwB;                                                \
    Pa[t_j & 1][1][1][pidx] = lwB;                                                \
    lds_barrier();                                                                \
    const bf16x8 ahA0 = *reinterpret_cast<const bf16x8*>(&Pa[t_j & 1][0][0][aidx]);       \
    const bf16x8 alA0 = *reinterpret_cast<const bf16x8*>(&Pa[t_j & 1][1][0][aidx]);       \
    const bf16x8 ahA1 = *reinterpret_cast<const bf16x8*>(&Pa[t_j & 1][0][0][aidx + 264]); \
    const bf16x8 alA1 = *reinterpret_cast<const bf16x8*>(&Pa[t_j & 1][1][0][aidx + 264]); \
    const bf16x8 ahB0 = *reinterpret_cast<const bf16x8*>(&Pa[t_j & 1][0][1][aidx]);       \
    const bf16x8 alB0 = *reinterpret_cast<const bf16x8*>(&Pa[t_j & 1][1][1][aidx]);       \
    const bf16x8 ahB1 = *reinterpret_cast<const bf16x8*>(&Pa[t_j & 1][0][1][aidx + 264]); \
    const bf16x8 alB1 = *reinterpret_cast<const bf16x8*>(&Pa[t_j & 1][1][1][aidx + 264]); \
    accA = __builtin_amdgcn_mfma_f32_32x32x16_bf16(alA0, BH0C, accA, 0, 0, 0);    \
    accB = __builtin_amdgcn_mfma_f32_32x32x16_bf16(alB0, BH0C, accB, 0, 0, 0);    \
    accA = __builtin_amdgcn_mfma_f32_32x32x16_bf16(ahA0, BL0C, accA, 0, 0, 0);    \
    accB = __builtin_amdgcn_mfma_f32_32x32x16_bf16(ahB0, BL0C, accB, 0, 0, 0);    \
    accA = __builtin_amdgcn_mfma_f32_32x32x16_bf16(ahA0, BH0C, accA, 0, 0, 0);    \
    accB = __builtin_amdgcn_mfma_f32_32x32x16_bf16(ahB0, BH0C, accB, 0, 0, 0);    \
    accA = __builtin_amdgcn_mfma_f32_32x32x16_bf16(alA1, BH1C, accA, 0, 0, 0);    \
    accB = __builtin_amdgcn_mfma_f32_32x32x16_bf16(alB1, BH1C, accB, 0, 0, 0);    \
    accA = __builtin_amdgcn_mfma_f32_32x32x16_bf16(ahA1, BL1C, accA, 0, 0, 0);    \
    accB = __builtin_amdgcn_mfma_f32_32x32x16_bf16(ahB1, BL1C, accB, 0, 0, 0);    \
    accA = __builtin_amdgcn_mfma_f32_32x32x16_bf16(ahA1, BH1C, accA, 0, 0, 0);    \
    accB = __builtin_amdgcn_mfma_f32_32x32x16_bf16(ahB1, BH1C, accB, 0, 0, 0);    \
  }

  for (int tj = 0; tj < NT; tj += 2) {
    STEP1(tj,     MA_e, mkA_e, MB_e, mkB_e, nv_e, bh0_e, bl0_e, bh1_e, bl1_e, bh0_o, bl0_o, bh1_o, bl1_o)
    STEP1(tj + 1, MA_o, mkA_o, MB_o, mkB_o, nv_o, bh0_o, bl0_o, bh1_o, bl1_o, bh0_e, bl0_e, bh1_e, bl1_e)
  }
#undef STEP1

  #pragma unroll
  for (int off = 1; off < 32; off <<= 1) {
    rsumA += __shfl_xor(rsumA, off);
    rsumB += __shfl_xor(rsumB, off);
  }
  if (p2 == 0) { l_lds[r] = rsumA; l_lds[32 + r] = rsumB; }
  __syncthreads();
  if (t < 64) pL[(size_t)jh * 8192 + i0 + t] = l_lds[t];

  // k-half reduce via LDS scratch (reuse nvs, 32KB), rowgroup A then B.
  float* scratch = nvs;
  if (ks == 1) {
    #pragma unroll
    for (int reg = 0; reg < 16; ++reg) scratch[cf * 1024 + reg * 64 + lane] = accA[reg];
  }
  __syncthreads();
  if (ks == 0) {
    #pragma unroll
    for (int reg = 0; reg < 16; ++reg) {
      const int row = (reg & 3) + 8 * (reg >> 2) + 4 * (lane >> 5);
      pO[(size_t)jh * 8192 * F + (size_t)(i0 + row) * F + col] =
          accA[reg] + scratch[cf * 1024 + reg * 64 + lane];
    }
  }
  __syncthreads();
  if (ks == 1) {
    #pragma unroll
    for (int reg = 0; reg < 16; ++reg) scratch[cf * 1024 + reg * 64 + lane] = accB[reg];
  }
  __syncthreads();
  if (ks == 0) {
    #pragma unroll
    for (int reg = 0; reg < 16; ++reg) {
      const int row = (reg & 3) + 8 * (reg >> 2) + 4 * (lane >> 5);
      pO[(size_t)jh * 8192 * F + (size_t)(i0 + 32 + row) * F + col] =
          accB[reg] + scratch[cf * 1024 + reg * 64 + lane];
    }
  }
}

// ---------------------------------------------------------------------------
// Layer-2 fused attention. Grid (128,2): 64 rows x j-half, 1024 thr.
// Wave w: rb = w&1 (16-row frag), cf = (w>>1)&3 (16-col frag), ks = w>>3.
// Per STEP: 6 MFMAs (2 rowgroups x bf16x3), B loaded once. Partial outputs.
// ---------------------------------------------------------------------------
__global__ __launch_bounds__(1024, 4) void attn2_kernel(
    const float* __restrict__ Mm, const uint* __restrict__ Bm,
    const float* __restrict__ sv, const float* __restrict__ nv,
    const unsigned short* __restrict__ Th, const unsigned short* __restrict__ Tl,
    float* __restrict__ pO, float* __restrict__ pL) {
  constexpr int F = 64, NT = 4096 / 64;
  __shared__ __align__(16) uint Pa[2][2][2][8 * 132];
  __shared__ __align__(16) float nvs[4096];
  __shared__ float l_lds[64];

  const int t = threadIdx.x;
  const int lane = t & 63;
  const int w = t >> 6;
  const int rb = w & 1;
  const int cf = (w >> 1) & 3;
  const int ks = w >> 3;
  const int r = t >> 5;
  const int p2 = t & 31;
  const int i0 = blockIdx.x * 64;
  const int jh = blockIdx.y;
  const size_t jbase = (size_t)jh * 4096;
  const int jt = jh * 128;

  reinterpret_cast<float4*>(nvs)[t] = reinterpret_cast<const float4*>(nv + jbase)[t];

  const float svrA = sv[i0 + r];
  const float svrB = sv[i0 + 32 + r];
  const size_t mrowA = (size_t)(i0 + r) * NN + jbase;
  const size_t mrowB = mrowA + (size_t)32 * NN;
  const uint* mkrowA = Bm + (size_t)(i0 + r) * (NN / 32) + jh * 128;
  const uint* mkrowB = mkrowA + (size_t)32 * (NN / 32);
  const int col = cf * 16 + (lane & 15);
  const size_t bo2 = ((size_t)(lane >> 4) * F + col) * 8;
  const int pidx = (p2 >> 2) * 132 + r * 4 + (p2 & 3);
  const int aidx = (ks * 4 + (lane >> 4)) * 132 + (rb * 16 + (lane & 15)) * 4;

  float2 MA_e = *reinterpret_cast<const float2*>(&Mm[mrowA + 2 * p2]);
  float2 MA_o = *reinterpret_cast<const float2*>(&Mm[mrowA + 64 + 2 * p2]);
  float2 MB_e = *reinterpret_cast<const float2*>(&Mm[mrowB + 2 * p2]);
  float2 MB_o = *reinterpret_cast<const float2*>(&Mm[mrowB + 64 + 2 * p2]);
  uint mkA_e = mkrowA[p2 >> 4];
  uint mkA_o = mkrowA[2 + (p2 >> 4)];
  uint mkB_e = mkrowB[p2 >> 4];
  uint mkB_o = mkrowB[2 + (p2 >> 4)];
  const size_t tb0 = (size_t)(jt + ks) * 2048;
  bf16x8 bh_e = *reinterpret_cast<const bf16x8*>(Th + tb0 + bo2);
  bf16x8 bl_e = *reinterpret_cast<const bf16x8*>(Tl + tb0 + bo2);
  bf16x8 bh_o, bl_o;

  float rsumA = 0.f, rsumB = 0.f;
  f32x4 accA = {0.f, 0.f, 0.f, 0.f}, accA2 = {0.f, 0.f, 0.f, 0.f};
  f32x4 accB = {0.f, 0.f, 0.f, 0.f}, accB2 = {0.f, 0.f, 0.f, 0.f};

  __syncthreads();   // nvs staged

  float2 nv_e = *reinterpret_cast<const float2*>(&nvs[2 * p2]);
  float2 nv_o = *reinterpret_cast<const float2*>(&nvs[64 + 2 * p2]);

#define STEP2(TJ, MCA, MKA, MCB, MKB, NVC, BHC, BLC, BHN, BLN)                    \
  {                                                                               \
    const int t_j = (TJ);                                                         \
    const int jb = (t_j + 1 < NT) ? t_j + 1 : 0;                                  \
    const size_t tb = (size_t)(jt + 2 * jb + ks) * 2048;                          \
    BHN = *reinterpret_cast<const bf16x8*>(Th + tb + bo2);                        \
    BLN = *reinterpret_cast<const bf16x8*>(Tl + tb + bo2);                        \
    float e0 = (svrA + NVC.x) * MCA.x; e0 = fmaxf(e0, 0.2f * e0); e0 = fminf(e0, 70.f); \
    float e1 = (svrA + NVC.y) * MCA.y; e1 = fmaxf(e1, 0.2f * e1); e1 = fminf(e1, 70.f); \
    float e2 = (svrB + NVC.x) * MCB.x; e2 = fmaxf(e2, 0.2f * e2); e2 = fminf(e2, 70.f); \
    float e3 = (svrB + NVC.y) * MCB.y; e3 = fmaxf(e3, 0.2f * e3); e3 = fminf(e3, 70.f); \
    const float pA0 = ((MKA >> (2 * (p2 & 15))) & 1u) ? __expf(e0) : 0.f;         \
    const float pA1 = ((MKA >> (2 * (p2 & 15) + 1)) & 1u) ? __expf(e1) : 0.f;     \
    const float pB0 = ((MKB >> (2 * (p2 & 15))) & 1u) ? __expf(e2) : 0.f;         \
    const float pB1 = ((MKB >> (2 * (p2 & 15) + 1)) & 1u) ? __expf(e3) : 0.f;     \
    rsumA += pA0 + pA1; rsumB += pB0 + pB1;                                       \
    const int jm = (t_j + 2 < NT) ? t_j + 2 : 0;                                  \
    MCA = *reinterpret_cast<const float2*>(&Mm[mrowA + (size_t)jm * 64 + 2 * p2]); \
    MKA = mkrowA[jm * 2 + (p2 >> 4)];                                             \
    MCB = *reinterpret_cast<const float2*>(&Mm[mrowB + (size_t)jm * 64 + 2 * p2]); \
    MKB = mkrowB[jm * 2 + (p2 >> 4)];                                             \
    NVC = *reinterpret_cast<const float2*>(&nvs[jm * 64 + 2 * p2]);               \
    const uint hwA = cvt_pk_bf16(pA0, pA1);                                       \
    const uint lwA = cvt_pk_bf16(pA0 - __uint_as_float(hwA << 16),                \
                                 pA1 - __uint_as_float(hwA & 0xffff0000u));       \
    const uint hwB = cvt_pk_bf16(pB0, pB1);                                       \
    const uint lwB = cvt_pk_bf16(pB0 - __uint_as_float(hwB << 16),                \
                                 pB1 - __uint_as_float(hwB & 0xffff0000u));       \
    Pa[t_j & 1][0][0][pidx] = hwA;                                                \
    Pa[t_j & 1][1][0][pidx] = lwA;                                                \
    Pa[t_j & 1][0][1][pidx] = hwB;                                                \
    Pa[t_j & 1][1][1][pidx] = lwB;                                                \
    lds_barrier();                                                                \
    const bf16x8 ahA = *reinterpret_cast<const bf16x8*>(&Pa[t_j & 1][0][0][aidx]); \
    const bf16x8 alA = *reinterpret_cast<const bf16x8*>(&Pa[t_j & 1][1][0][aidx]); \
    const bf16x8 ahB = *reinterpret_cast<const bf16x8*>(&Pa[t_j & 1][0][1][aidx]); \
    const bf16x8 alB = *reinterpret_cast<const bf16x8*>(&Pa[t_j & 1][1][1][aidx]); \
    accA  = __builtin_amdgcn_mfma_f32_16x16x32_bf16(alA, BHC, accA, 0, 0, 0);     \
    accB  = __builtin_amdgcn_mfma_f32_16x16x32_bf16(alB, BHC, accB, 0, 0, 0);     \
    accA2 = __builtin_amdgcn_mfma_f32_16x16x32_bf16(ahA, BLC, accA2, 0, 0, 0);    \
    accB2 = __builtin_amdgcn_mfma_f32_16x16x32_bf16(ahB, BLC, accB2, 0, 0, 0);    \
    accA  = __builtin_amdgcn_mfma_f32_16x16x32_bf16(ahA, BHC, accA, 0, 0, 0);     \
    accB  = __builtin_amdgcn_mfma_f32_16x16x32_bf16(ahB, BHC, accB, 0, 0, 0);     \
  }

  for (int tj = 0; tj < NT; tj += 2) {
    STEP2(tj,     MA_e, mkA_e, MB_e, mkB_e, nv_e, bh_e, bl_e, bh_o, bl_o)
    STEP2(tj + 1, MA_o, mkA_o, MB_o, mkB_o, nv_o, bh_o, bl_o, bh_e, bl_e)
  }
#undef STEP2

  #pragma unroll
  for (int off = 1; off < 32; off <<= 1) {
    rsumA += __shfl_xor(rsumA, off);
    rsumB += __shfl_xor(rsumB, off);
  }
  if (p2 == 0) { l_lds[r] = rsumA; l_lds[32 + r] = rsumB; }
  __syncthreads();
  if (t < 64) pL[(size_t)jh * 8192 + i0 + t] = l_lds[t];

  float* scratch = nvs;
  if (ks == 1) {
    #pragma unroll
    for (int reg = 0; reg < 4; ++reg)
      scratch[(w & 7) * 256 + reg * 64 + lane] = accA[reg] + accA2[reg];
  }
  __syncthreads();
  if (ks == 0) {
    #pragma unroll
    for (int reg = 0; reg < 4; ++reg) {
      const int row = rb * 16 + (lane >> 4) * 4 + reg;
      pO[(size_t)jh * 8192 * F + (size_t)(i0 + row) * F + col] =
          accA[reg] + accA2[reg] + scratch[(w & 7) * 256 + reg * 64 + lane];
    }
  }
  __syncthreads();
  if (ks == 1) {
    #pragma unroll
    for (int reg = 0; reg < 4; ++reg)
      scratch[(w & 7) * 256 + reg * 64 + lane] = accB[reg] + accB2[reg];
  }
  __syncthreads();
  if (ks == 0) {
    #pragma unroll
    for (int reg = 0; reg < 4; ++reg) {
      const int row = rb * 16 + (lane >> 4) * 4 + reg;
      pO[(size_t)jh * 8192 * F + (size_t)(i0 + 32 + row) * F + col] =
          accB[reg] + accB2[reg] + scratch[(w & 7) * 256 + reg * 64 + lane];
    }
  }
}

// ---------------------------------------------------------------------------
extern "C" void kernel_launch(void* const* d_in, const int* in_sizes, int n_in,
                              void* d_out, int out_size, void* d_ws, size_t ws_size,
                              hipStream_t stream) {
  const float* x   = (const float*)d_in[0];
  const int*   adj = (const int*)  d_in[1];
  const float* Mm  = (const float*)d_in[2];
  const float* W0  = (const float*)d_in[3];
  const float* as0 = (const float*)d_in[4];
  const float* an0 = (const float*)d_in[5];
  const float* W1  = (const float*)d_in[6];
  const float* as1 = (const float*)d_in[7];
  const float* an1 = (const float*)d_in[8];
  float* out = (float*)d_out;

  char* ws = (char*)d_ws;
  const size_t MB = 1048576;
  const size_t KB = 1024;
  float* h0  = (float*)(ws);                              // 8 MB (dead after split1)
  uint*  Bm  = (uint*) (ws);                              // 8 MB (written after split1)
  float* x1  = (float*)(ws + 8 * MB);                     // 8 MB
  float* h1  = (float*)(ws + 16 * MB);                    // 2 MB
  unsigned short* Th0 = (unsigned short*)(ws + 18 * MB);  // 4 MB
  unsigned short* Tl0 = (unsigned short*)(ws + 22 * MB);  // 4 MB
  unsigned short* Th1 = (unsigned short*)(ws + 26 * MB);  // 1 MB
  unsigned short* Tl1 = (unsigned short*)(ws + 27 * MB);  // 1 MB
  float* s0  = (float*)(ws + 28 * MB);
  float* n0  = (float*)(ws + 28 * MB + 32 * KB);
  float* s1  = (float*)(ws + 28 * MB + 64 * KB);
  float* n1  = (float*)(ws + 28 * MB + 96 * KB);
  float* pL1 = (float*)(ws + 28 * MB + 128 * KB);         // 64 KB [2][8192]
  float* pL2 = (float*)(ws + 28 * MB + 192 * KB);         // 64 KB
  float* pO1 = (float*)(ws + 29 * MB);                    // 16 MB [2][8192][256]
  float* pO2 = (float*)(ws + 29 * MB);                    // 4 MB  [2][8192][64] (pO1 dead by then)

  // ---- layer 1 ----
  gemm_kernel<512, 256><<<dim3(128, 4), dim3(256), 0, stream>>>(x, W0, h0);
  sn_kernel<256><<<dim3(2048), dim3(256), 0, stream>>>(h0, as0, an0, s0, n0);
  split_kernel<256><<<dim3(256), dim3(256), 0, stream>>>(h0, Th0, Tl0);
  mask_kernel<<<dim3(65536), dim3(256), 0, stream>>>(adj, Bm);   // h0 now dead
  attn1_kernel<<<dim3(128, 2), dim3(1024), 0, stream>>>(Mm, Bm, s0, n0, Th0, Tl0, pO1, pL1);
  combine_kernel<256><<<dim3(2048), dim3(256), 0, stream>>>(pO1, pL1, x1);
  // ---- layer 2 ----
  gemm_kernel<256, 64><<<dim3(128, 1), dim3(256), 0, stream>>>(x1, W1, h1);
  sn_kernel<64><<<dim3(2048), dim3(256), 0, stream>>>(h1, as1, an1, s1, n1);
  split_kernel<64><<<dim3(256), dim3(256), 0, stream>>>(h1, Th1, Tl1);
  attn2_kernel<<<dim3(128, 2), dim3(1024), 0, stream>>>(Mm, Bm, s1, n1, Th1, Tl1, pO2, pL2);
  combine_kernel<64><<<dim3(512), dim3(256), 0, stream>>>(pO2, pL2, out);
}